// Round 16
// baseline (181.423 us; speedup 1.0000x reference)
//
#include <hip/hip_runtime.h>
#include <type_traits>

typedef short bf16x4 __attribute__((ext_vector_type(4)));
typedef short bf16x8 __attribute__((ext_vector_type(8)));
typedef float f32x4 __attribute__((ext_vector_type(4)));
typedef float f32x8 __attribute__((ext_vector_type(8)));
typedef float f32x16 __attribute__((ext_vector_type(16)));

__device__ __forceinline__ unsigned short f2bf(float f) {
  union { float f; unsigned int u; } v; v.f = f;
  unsigned int r = v.u + 0x7FFFu + ((v.u >> 16) & 1u);
  return (unsigned short)(r >> 16);
}

__device__ __forceinline__ float exp2_fast(float x) {
  float r;
  asm("v_exp_f32 %0, %1" : "=v"(r) : "v"(x));
  return r;
}

__device__ __forceinline__ unsigned int cvt_pk_bf16(float lo, float hi) {
  unsigned int r;
  asm("v_cvt_pk_bf16_f32 %0, %1, %2" : "=v"(r) : "v"(lo), "v"(hi));
  return r;
}

// ---------------- prep kernels ----------------

// in [R][C] fp32 -> out [C][R] bf16
__global__ __launch_bounds__(256) void k_transpose_bf16(const float* __restrict__ in,
                                                        unsigned short* __restrict__ out,
                                                        int R, int C) {
  __shared__ float tile[32][33];
  int tx = threadIdx.x, ty = threadIdx.y;
  int c0 = blockIdx.x * 32, r0 = blockIdx.y * 32;
#pragma unroll
  for (int i = 0; i < 32; i += 8) tile[ty + i][tx] = in[(size_t)(r0 + ty + i) * C + c0 + tx];
  __syncthreads();
#pragma unroll
  for (int i = 0; i < 32; i += 8) out[(size_t)(c0 + ty + i) * R + r0 + tx] = f2bf(tile[tx][ty + i]);
}

// bias_table [4095][16] -> biash [16][4096], scaled by log2(e)
__global__ __launch_bounds__(256) void k_bias_cols(const float* __restrict__ bt,
                                                   float* __restrict__ bh) {
  int i = blockIdx.x * 256 + threadIdx.x;
  if (i < 4095 * 16) bh[(i & 15) * 4096 + (i >> 4)] = bt[i] * 1.44269504089f;
}

// ---------------- GEMM: C[M][N] = A[M][1024] * Bt[N][1024]^T (+bias) ----------------
// 8 waves / 512 threads, 128x128 tile, wave tile 64x32. Reg-staged depth-2 pipeline.
// EPI==1: A is fp32 (x) — converted to bf16 in-register during SWRITE (fused convert).
template <int EPI>
__global__ __launch_bounds__(512) void k_gemm(const void* __restrict__ Ain,
                                              const unsigned short* __restrict__ Bt,
                                              const float* __restrict__ bias,
                                              float* __restrict__ Cf,
                                              unsigned short* __restrict__ qb,
                                              unsigned short* __restrict__ kb,
                                              unsigned short* __restrict__ vtb) {
  __shared__ unsigned short Alds[2][128 * 64];
  __shared__ unsigned short Blds[2][128 * 64];
  const int t = threadIdx.x;
  const int l = t & 63, w = t >> 6;
  const int l15 = l & 15, l4 = l >> 4;
  const int wm = w >> 2, wn = w & 3;

  const int hwid = blockIdx.x;
  const int x = hwid & 7, loc = hwid >> 3;
  const int bm = ((x >> 1) * 8 + (loc & 7)) * 128;
  const int bn = ((x & 1) * (EPI ? 12 : 4) + (loc >> 3)) * 128;

  const int srow = t >> 3;
  const int sc = t & 7;
  using AELT = typename std::conditional<EPI == 1, float, unsigned short>::type;
  using AREG = typename std::conditional<EPI == 1, f32x8, bf16x8>::type;
  const AELT* aglp = ((const AELT*)Ain) + (size_t)(bm + srow) * 1024 + sc * 8;
  const unsigned short* bgl = Bt + (size_t)(bn + srow) * 1024 + sc * 8;
  const int wls = srow * 64 + ((sc ^ (srow & 7)) * 8);

  f32x4 acc[4][2];
#pragma unroll
  for (int i = 0; i < 4; ++i)
#pragma unroll
    for (int j = 0; j < 2; ++j) acc[i][j] = (f32x4){0.f, 0.f, 0.f, 0.f};

  AREG ra_a[2], rb_a[2];
  bf16x8 ra_b[2], rb_b[2];

#define GLOAD(RA, RB, KT)                                                     \
  _Pragma("unroll") for (int q = 0; q < 2; ++q) {                             \
    RA[q] = *(const AREG*)(aglp + (size_t)q * 65536 + (KT) * 64);             \
    RB[q] = *(const bf16x8*)(bgl + (size_t)q * 65536 + (KT) * 64);            \
  }
#define SWRITE(RA, RB, CUR)                                                   \
  _Pragma("unroll") for (int q = 0; q < 2; ++q) {                             \
    bf16x8 aw;                                                                \
    if constexpr (EPI == 1) {                                                 \
      union { unsigned int u[4]; bf16x8 v; } pk;                              \
      pk.u[0] = cvt_pk_bf16(RA[q][0], RA[q][1]);                              \
      pk.u[1] = cvt_pk_bf16(RA[q][2], RA[q][3]);                              \
      pk.u[2] = cvt_pk_bf16(RA[q][4], RA[q][5]);                              \
      pk.u[3] = cvt_pk_bf16(RA[q][6], RA[q][7]);                              \
      aw = pk.v;                                                              \
    } else {                                                                  \
      aw = RA[q];                                                             \
    }                                                                         \
    *(bf16x8*)&Alds[CUR][q * 4096 + wls] = aw;                                \
    *(bf16x8*)&Blds[CUR][q * 4096 + wls] = RB[q];                             \
  }

  GLOAD(ra_a, ra_b, 0);
  GLOAD(rb_a, rb_b, 1);
  SWRITE(ra_a, ra_b, 0);
  asm volatile("s_waitcnt lgkmcnt(0)" ::: "memory");
  __builtin_amdgcn_s_barrier();

#define GEMM_PHASE(KT, RFA, RFB, RPA, RPB)                                    \
  {                                                                           \
    const int cur_ = (KT) & 1;                                                \
    if ((KT) + 2 < 16) { GLOAD(RFA, RFB, (KT) + 2); }                         \
    __builtin_amdgcn_s_setprio(1);                                            \
    _Pragma("unroll") for (int kc = 0; kc < 2; ++kc) {                        \
      bf16x8 af[4], bv[2];                                                    \
      _Pragma("unroll") for (int i = 0; i < 4; ++i) {                         \
        int ra_ = wm * 64 + i * 16 + l15;                                     \
        af[i] = *(const bf16x8*)&Alds[cur_][ra_ * 64 +                        \
                                            (((kc * 4 + l4) ^ (l15 & 7))) * 8]; \
      }                                                                       \
      _Pragma("unroll") for (int j = 0; j < 2; ++j) {                         \
        int rb_ = wn * 32 + j * 16 + l15;                                     \
        bv[j] = *(const bf16x8*)&Blds[cur_][rb_ * 64 +                        \
                                            (((kc * 4 + l4) ^ (l15 & 7))) * 8]; \
      }                                                                       \
      _Pragma("unroll") for (int i = 0; i < 4; ++i)                           \
        _Pragma("unroll") for (int jn = 0; jn < 2; ++jn)                      \
          acc[i][jn] =                                                        \
              __builtin_amdgcn_mfma_f32_16x16x32_bf16(af[i], bv[jn],          \
                                                      acc[i][jn], 0, 0, 0);   \
    }                                                                         \
    __builtin_amdgcn_s_setprio(0);                                            \
    if ((KT) + 1 < 16) { SWRITE(RPA, RPB, cur_ ^ 1); }                        \
    asm volatile("s_waitcnt lgkmcnt(0)" ::: "memory");                        \
    __builtin_amdgcn_s_barrier();                                             \
  }

  for (int kt = 0; kt < 16; kt += 2) {
    GEMM_PHASE(kt, ra_a, ra_b, rb_a, rb_b);
    GEMM_PHASE(kt + 1, rb_a, rb_b, ra_a, ra_b);
  }
#undef GEMM_PHASE
#undef SWRITE
#undef GLOAD

#pragma unroll
  for (int i = 0; i < 4; ++i) {
#pragma unroll
    for (int jn = 0; jn < 2; ++jn) {
      int n = bn + wn * 32 + jn * 16 + l15;
      float bval = bias[n];
#pragma unroll
      for (int j = 0; j < 4; ++j) {
        int m = bm + wm * 64 + i * 16 + l4 * 4 + j;
        float v = acc[i][jn][j] + bval;
        if (EPI == 0) {
          Cf[(size_t)m * 1024 + n] = v;
        } else {
          int which = n >> 10, hh = (n >> 6) & 15, d = n & 63;
          int bb = m >> 11, pos = m & 2047;
          int bhh = bb * 16 + hh;
          if (which == 0)
            qb[((size_t)bhh * 2048 + pos) * 64 + d] = f2bf(v * 0.18033688f);  // 0.125*log2(e)
          else if (which == 1)
            kb[((size_t)bhh * 2048 + pos) * 64 + d] = f2bf(v);
          else
            vtb[((size_t)bhh * 64 + d) * 2048 + pos] = f2bf(v);
        }
      }
    }
  }
}

// ---------------- flash attention core (shared by single-pass and KV-split) --------
// SPLIT==0: grid 512, 32 tiles, writes bf16 aout directly.
// SPLIT==1: grid 1024 (2 KV halves), 16 tiles, writes f32 partial (O,m,l).
template <int SPLIT>
__global__ __launch_bounds__(256) void k_attn(const unsigned short* __restrict__ qbuf,
                                              const unsigned short* __restrict__ kbuf,
                                              const unsigned short* __restrict__ vtbuf,
                                              const float* __restrict__ biash,
                                              unsigned short* __restrict__ aout,
                                              float* __restrict__ Opart,
                                              float* __restrict__ mlpart) {
  __shared__ __align__(16) unsigned short Klds[2][64 * 64];
  __shared__ __align__(16) unsigned short Vlds[2][64 * 64];

  const int t = threadIdx.x;
  const int w = t >> 6, l = t & 63;
  const int l31 = l & 31, hi = l >> 5;

  // XCD swizzle; SPLIT=1 adds the kv-half bit (4 bh per XCD in both cases)
  const int bid = blockIdx.x;
  int qt, bh, half;
  if (SPLIT) {
    const int loc = bid >> 3;                 // 0..127
    bh = (bid & 7) * 4 + (loc >> 5);
    qt = loc & 15;
    half = (loc >> 4) & 1;
  } else {
    const int swzb = (bid & 7) * 64 + (bid >> 3);
    qt = swzb & 15;
    bh = swzb >> 4;
    half = 0;
  }
  const int h = bh & 15, b = bh >> 4;
  const int qbase = qt * 128;
  const int wq = qbase + w * 32;
  const int NT = SPLIT ? 16 : 32;

  // Q B-operand regs: lane l31 = q-col, slot (hi,e) = d = 16*ds + 8*hi + e
  bf16x8 qB[4];
  {
    const unsigned short* qrow = qbuf + ((size_t)bh * 2048 + wq + l31) * 64;
#pragma unroll
    for (int ds = 0; ds < 4; ++ds) qB[ds] = *(const bf16x8*)&qrow[ds * 16 + hi * 8];
  }

  f32x16 O[2];
#pragma unroll
  for (int i = 0; i < 16; ++i) { O[0][i] = 0.f; O[1][i] = 0.f; }
  float m_run = -3e38f, l_run = 0.f;

  // staging: linear global source; swizzled LDS write offset
  const int c0r = t >> 3, c0c = t & 7;
  const unsigned short* kg =
      kbuf + ((size_t)bh * 2048 + half * 1024 + c0r) * 64 + c0c * 8;
  const unsigned short* vg =
      vtbuf + ((size_t)bh * 64 + c0r) * 2048 + half * 1024 + c0c * 8;
  const int wKV = c0r * 64 + ((c0c ^ (c0r & 7)) * 8);

  // prologue: stage tile 0 of this half
  {
    bf16x8 k0 = *(const bf16x8*)(kg);
    bf16x8 k1 = *(const bf16x8*)(kg + 32 * 64);
    bf16x8 v0 = *(const bf16x8*)(vg);
    bf16x8 v1 = *(const bf16x8*)(vg + 32 * 2048);
    *(bf16x8*)&Klds[0][wKV] = k0;
    *(bf16x8*)&Klds[0][wKV + 2048] = k1;
    *(bf16x8*)&Vlds[0][wKV] = v0;
    *(bf16x8*)&Vlds[0][wKV + 2048] = v1;
  }
  __syncthreads();

  // per-lane global bias base: value(kt2,g,r) = bgl[(half*1024)+kt*64 + 32*kt2 + 8*g + r]
  const float* bgl = biash + h * 4096 + 2047 - (wq + l31) + 4 * hi + half * 1024;

  for (int kt = 0; kt < NT; ++kt) {
    const int cur = kt & 1;

    bf16x8 kst0, kst1, vst0, vst1;
    if (kt < NT - 1) {
      const unsigned short* kga = kg + (size_t)(kt + 1) * 4096;
      const unsigned short* vga = vg + (kt + 1) * 64;
      kst0 = *(const bf16x8*)(kga);
      kst1 = *(const bf16x8*)(kga + 32 * 64);
      vst0 = *(const bf16x8*)(vga);
      vst1 = *(const bf16x8*)(vga + 32 * 2048);
    }
    const int kbase = kt * 64;

    f32x4 bq[2][4];
#pragma unroll
    for (int kt2 = 0; kt2 < 2; ++kt2)
#pragma unroll
      for (int g = 0; g < 4; ++g)
        __builtin_memcpy(&bq[kt2][g], &bgl[kbase + 32 * kt2 + 8 * g], 16);

    // QK^T swapped
    f32x16 sacc[2];
#pragma unroll
    for (int i = 0; i < 16; ++i) { sacc[0][i] = 0.f; sacc[1][i] = 0.f; }
    __builtin_amdgcn_s_setprio(1);
#pragma unroll
    for (int kt2 = 0; kt2 < 2; ++kt2) {
      int row = kt2 * 32 + l31;
      int rsw = row & 7;
#pragma unroll
      for (int ds = 0; ds < 4; ++ds) {
        bf16x8 ka = *(const bf16x8*)&Klds[cur][row * 64 + (((2 * ds + hi) ^ rsw) * 8)];
        sacc[kt2] = __builtin_amdgcn_mfma_f32_32x32x16_bf16(ka, qB[ds], sacc[kt2], 0, 0, 0);
      }
    }
    __builtin_amdgcn_s_setprio(0);

    // bias add
#pragma unroll
    for (int kt2 = 0; kt2 < 2; ++kt2)
#pragma unroll
      for (int g = 0; g < 4; ++g)
#pragma unroll
        for (int r = 0; r < 4; ++r) sacc[kt2][4 * g + r] += bq[kt2][g][r];

    // max
    float mx;
    {
      float q0 = fmaxf(fmaxf(sacc[0][0], sacc[0][1]), fmaxf(sacc[0][2], sacc[0][3]));
      float q1 = fmaxf(fmaxf(sacc[0][4], sacc[0][5]), fmaxf(sacc[0][6], sacc[0][7]));
      float q2 = fmaxf(fmaxf(sacc[0][8], sacc[0][9]), fmaxf(sacc[0][10], sacc[0][11]));
      float q3 = fmaxf(fmaxf(sacc[0][12], sacc[0][13]), fmaxf(sacc[0][14], sacc[0][15]));
      float q4 = fmaxf(fmaxf(sacc[1][0], sacc[1][1]), fmaxf(sacc[1][2], sacc[1][3]));
      float q5 = fmaxf(fmaxf(sacc[1][4], sacc[1][5]), fmaxf(sacc[1][6], sacc[1][7]));
      float q6 = fmaxf(fmaxf(sacc[1][8], sacc[1][9]), fmaxf(sacc[1][10], sacc[1][11]));
      float q7 = fmaxf(fmaxf(sacc[1][12], sacc[1][13]), fmaxf(sacc[1][14], sacc[1][15]));
      mx = fmaxf(fmaxf(fmaxf(q0, q1), fmaxf(q2, q3)), fmaxf(fmaxf(q4, q5), fmaxf(q6, q7)));
      mx = fmaxf(mx, __shfl_xor(mx, 32));
    }

    // defer-max rescale (THR=8, log2 domain)
    if (__any(mx > m_run + 8.f)) {
      float mnew = fmaxf(m_run, mx);
      float alpha = exp2_fast(m_run - mnew);
      m_run = mnew;
      l_run *= alpha;
#pragma unroll
      for (int g = 0; g < 4; ++g)
#pragma unroll
        for (int r = 0; r < 4; ++r) {
          float a_lo = __shfl(alpha, 8 * g + r);
          float a_hi = __shfl(alpha, 8 * g + r + 4);
          float aq = hi ? a_hi : a_lo;
          O[0][4 * g + r] *= aq;
          O[1][4 * g + r] *= aq;
        }
    }

    // exp + row-sum
#pragma unroll
    for (int kt2 = 0; kt2 < 2; ++kt2)
#pragma unroll
      for (int i = 0; i < 16; ++i) sacc[kt2][i] = exp2_fast(sacc[kt2][i] - m_run);
    {
      float s0 = (sacc[0][0] + sacc[0][1]) + (sacc[0][2] + sacc[0][3]);
      float s1 = (sacc[0][4] + sacc[0][5]) + (sacc[0][6] + sacc[0][7]);
      float s2 = (sacc[0][8] + sacc[0][9]) + (sacc[0][10] + sacc[0][11]);
      float s3 = (sacc[0][12] + sacc[0][13]) + (sacc[0][14] + sacc[0][15]);
      float s4 = (sacc[1][0] + sacc[1][1]) + (sacc[1][2] + sacc[1][3]);
      float s5 = (sacc[1][4] + sacc[1][5]) + (sacc[1][6] + sacc[1][7]);
      float s6 = (sacc[1][8] + sacc[1][9]) + (sacc[1][10] + sacc[1][11]);
      float s7 = (sacc[1][12] + sacc[1][13]) + (sacc[1][14] + sacc[1][15]);
      float rs = ((s0 + s1) + (s2 + s3)) + ((s4 + s5) + (s6 + s7));
      rs += __shfl_xor(rs, 32);
      l_run += rs;
    }

    // P pack
    bf16x8 pa[2][2];
#pragma unroll
    for (int kt2 = 0; kt2 < 2; ++kt2)
#pragma unroll
      for (int mm = 0; mm < 2; ++mm) {
        union { unsigned int u[4]; bf16x8 v; } pk;
        pk.u[0] = cvt_pk_bf16(sacc[kt2][8 * mm + 0], sacc[kt2][8 * mm + 1]);
        pk.u[1] = cvt_pk_bf16(sacc[kt2][8 * mm + 2], sacc[kt2][8 * mm + 3]);
        pk.u[2] = cvt_pk_bf16(sacc[kt2][8 * mm + 4], sacc[kt2][8 * mm + 5]);
        pk.u[3] = cvt_pk_bf16(sacc[kt2][8 * mm + 6], sacc[kt2][8 * mm + 7]);
        pa[kt2][mm] = pk.v;
      }

    // PV
    __builtin_amdgcn_s_setprio(1);
#pragma unroll
    for (int dt = 0; dt < 2; ++dt) {
      int row = dt * 32 + l31;
      int rsw = row & 7;
#pragma unroll
      for (int kt2 = 0; kt2 < 2; ++kt2)
#pragma unroll
        for (int mm = 0; mm < 2; ++mm) {
          int cA = (4 * kt2 + 2 * mm) ^ rsw;
          int cB = (4 * kt2 + 2 * mm + 1) ^ rsw;
          bf16x4 vlo = *(const bf16x4*)&Vlds[cur][row * 64 + cA * 8 + 4 * hi];
          bf16x4 vhi = *(const bf16x4*)&Vlds[cur][row * 64 + cB * 8 + 4 * hi];
          bf16x8 vb = __builtin_shufflevector(vlo, vhi, 0, 1, 2, 3, 4, 5, 6, 7);
          O[dt] = __builtin_amdgcn_mfma_f32_32x32x16_bf16(pa[kt2][mm], vb, O[dt], 0, 0, 0);
        }
    }
    __builtin_amdgcn_s_setprio(0);

    // write-late: publish next tile
    if (kt < NT - 1) {
      *(bf16x8*)&Klds[cur ^ 1][wKV] = kst0;
      *(bf16x8*)&Klds[cur ^ 1][wKV + 2048] = kst1;
      *(bf16x8*)&Vlds[cur ^ 1][wKV] = vst0;
      *(bf16x8*)&Vlds[cur ^ 1][wKV + 2048] = vst1;
    }
    __syncthreads();
  }

  if (SPLIT) {
    // write f32 partials: Opart[half][bh][q][d], mlpart[half][bh][q][{m,l}]
    float* obase = Opart + (((size_t)half * 32 + bh) * 2048) * 64;
#pragma unroll
    for (int g = 0; g < 4; ++g)
#pragma unroll
      for (int r = 0; r < 4; ++r) {
        int q = wq + 8 * g + r + 4 * hi;
        obase[(size_t)q * 64 + l31] = O[0][4 * g + r];
        obase[(size_t)q * 64 + 32 + l31] = O[1][4 * g + r];
      }
    if (hi == 0) {
      size_t mi = (((size_t)half * 32 + bh) * 2048 + wq + l31) * 2;
      mlpart[mi] = m_run;
      mlpart[mi + 1] = l_run;
    }
  } else {
    float linv = 1.f / l_run;
#pragma unroll
    for (int g = 0; g < 4; ++g)
#pragma unroll
      for (int r = 0; r < 4; ++r) {
        float v_lo = __shfl(linv, 8 * g + r);
        float v_hi = __shfl(linv, 8 * g + r + 4);
        float sc = hi ? v_hi : v_lo;
        int q = wq + 8 * g + r + 4 * hi;
        size_t base = ((size_t)b * 2048 + q) * 1024 + h * 64 + l31;
        aout[base] = f2bf(O[0][4 * g + r] * sc);
        aout[base + 32] = f2bf(O[1][4 * g + r] * sc);
      }
  }
}

// ---------------- KV-split merge: combine 2 halves (exp2 domain, exact f32) --------
// thread -> (bh, q, dq): 4 d-elements. grid 4096 x 256.
__global__ __launch_bounds__(256) void k_merge(const float* __restrict__ Opart,
                                               const float* __restrict__ mlpart,
                                               unsigned short* __restrict__ aout) {
  int id = blockIdx.x * 256 + threadIdx.x;
  int dq = id & 15;
  int q = (id >> 4) & 2047;
  int bh = id >> 15;
  int h = bh & 15, b = bh >> 4;

  size_t mi0 = (((size_t)bh) * 2048 + q) * 2;
  size_t mi1 = (((size_t)32 + bh) * 2048 + q) * 2;
  float m0 = mlpart[mi0], l0 = mlpart[mi0 + 1];
  float m1 = mlpart[mi1], l1 = mlpart[mi1 + 1];
  float m = fmaxf(m0, m1);
  float a0 = exp2_fast(m0 - m);
  float a1 = exp2_fast(m1 - m);
  float linv = 1.f / (l0 * a0 + l1 * a1);

  f32x4 o0, o1;
  __builtin_memcpy(&o0, Opart + (((size_t)bh) * 2048 + q) * 64 + dq * 4, 16);
  __builtin_memcpy(&o1, Opart + (((size_t)32 + bh) * 2048 + q) * 64 + dq * 4, 16);

  size_t base = ((size_t)b * 2048 + q) * 1024 + h * 64 + dq * 4;
#pragma unroll
  for (int j = 0; j < 4; ++j)
    aout[base + j] = f2bf((o0[j] * a0 + o1[j] * a1) * linv);
}

// ---------------- launch ----------------

extern "C" void kernel_launch(void* const* d_in, const int* in_sizes, int n_in,
                              void* d_out, int out_size, void* d_ws, size_t ws_size,
                              hipStream_t stream) {
  const float* x = (const float*)d_in[0];
  const float* qkv_w = (const float*)d_in[1];
  const float* qkv_b = (const float*)d_in[2];
  const float* proj_w = (const float*)d_in[3];
  const float* proj_b = (const float*)d_in[4];
  const float* bias_table = (const float*)d_in[5];
  float* out = (float*)d_out;

  char* ws = (char*)d_ws;
  unsigned short* attn_out = (unsigned short*)(ws);                    // 8 MB
  unsigned short* wqkv = (unsigned short*)(ws + (size_t)(8u << 20));   // 6 MB
  unsigned short* wproj = (unsigned short*)(ws + (size_t)(14u << 20)); // 2 MB
  unsigned short* qb = (unsigned short*)(ws + (size_t)(16u << 20));    // 8 MB
  unsigned short* kb = (unsigned short*)(ws + (size_t)(24u << 20));    // 8 MB
  unsigned short* vtb = (unsigned short*)(ws + (size_t)(32u << 20));   // 8 MB
  float* biash = (float*)(ws + (size_t)(40u << 20));                   // 256 KB
  float* Opart = (float*)(ws + (size_t)(41u << 20));                   // 33.6 MB
  float* mlpart = (float*)(ws + (size_t)(76u << 20));                  // 2 MB
  const size_t ws_need = (size_t)(79u << 20);

  k_transpose_bf16<<<dim3(96, 32), dim3(32, 8), 0, stream>>>(qkv_w, wqkv, 1024, 3072);
  k_transpose_bf16<<<dim3(32, 32), dim3(32, 8), 0, stream>>>(proj_w, wproj, 1024, 1024);
  k_bias_cols<<<dim3(256), dim3(256), 0, stream>>>(bias_table, biash);

  k_gemm<1><<<dim3(768), dim3(512), 0, stream>>>((const void*)x, wqkv, qkv_b, nullptr, qb, kb,
                                                 vtb);
  if (ws_size >= ws_need) {
    k_attn<1><<<dim3(1024), dim3(256), 0, stream>>>(qb, kb, vtb, biash, nullptr, Opart, mlpart);
    k_merge<<<dim3(4096), dim3(256), 0, stream>>>(Opart, mlpart, attn_out);
  } else {
    k_attn<0><<<dim3(512), dim3(256), 0, stream>>>(qb, kb, vtb, biash, attn_out, nullptr,
                                                   nullptr);
  }
  k_gemm<0><<<dim3(256), dim3(512), 0, stream>>>((const void*)attn_out, wproj, proj_b, out,
                                                 nullptr, nullptr, nullptr);
}

// Round 17
// 137.650 us; speedup vs baseline: 1.3180x; 1.3180x over previous
//
#include <hip/hip_runtime.h>
#include <type_traits>

typedef short bf16x4 __attribute__((ext_vector_type(4)));
typedef short bf16x8 __attribute__((ext_vector_type(8)));
typedef float f32x4 __attribute__((ext_vector_type(4)));
typedef float f32x8 __attribute__((ext_vector_type(8)));
typedef float f32x16 __attribute__((ext_vector_type(16)));

__device__ __forceinline__ unsigned short f2bf(float f) {
  union { float f; unsigned int u; } v; v.f = f;
  unsigned int r = v.u + 0x7FFFu + ((v.u >> 16) & 1u);
  return (unsigned short)(r >> 16);
}

__device__ __forceinline__ float exp2_fast(float x) {
  float r;
  asm("v_exp_f32 %0, %1" : "=v"(r) : "v"(x));
  return r;
}

__device__ __forceinline__ unsigned int cvt_pk_bf16(float lo, float hi) {
  unsigned int r;
  asm("v_cvt_pk_bf16_f32 %0, %1, %2" : "=v"(r) : "v"(lo), "v"(hi));
  return r;
}

// ---------------- prep kernels ----------------

// in [R][C] fp32 -> out [C][R] bf16
__global__ __launch_bounds__(256) void k_transpose_bf16(const float* __restrict__ in,
                                                        unsigned short* __restrict__ out,
                                                        int R, int C) {
  __shared__ float tile[32][33];
  int tx = threadIdx.x, ty = threadIdx.y;
  int c0 = blockIdx.x * 32, r0 = blockIdx.y * 32;
#pragma unroll
  for (int i = 0; i < 32; i += 8) tile[ty + i][tx] = in[(size_t)(r0 + ty + i) * C + c0 + tx];
  __syncthreads();
#pragma unroll
  for (int i = 0; i < 32; i += 8) out[(size_t)(c0 + ty + i) * R + r0 + tx] = f2bf(tile[tx][ty + i]);
}

// bias_table [4095][16] -> biash [16][4096], scaled by log2(e)
__global__ __launch_bounds__(256) void k_bias_cols(const float* __restrict__ bt,
                                                   float* __restrict__ bh) {
  int i = blockIdx.x * 256 + threadIdx.x;
  if (i < 4095 * 16) bh[(i & 15) * 4096 + (i >> 4)] = bt[i] * 1.44269504089f;
}

// ---------------- GEMM: C[M][N] = A[M][1024] * Bt[N][1024]^T (+bias) ----------------
// 8 waves / 512 threads, 128x128 tile, wave tile 64x32. Reg-staged depth-2 pipeline.
// EPI==1: A is fp32 (x) — converted to bf16 in-register during SWRITE (fused convert).
template <int EPI>
__global__ __launch_bounds__(512) void k_gemm(const void* __restrict__ Ain,
                                              const unsigned short* __restrict__ Bt,
                                              const float* __restrict__ bias,
                                              float* __restrict__ Cf,
                                              unsigned short* __restrict__ qb,
                                              unsigned short* __restrict__ kb,
                                              unsigned short* __restrict__ vtb) {
  __shared__ unsigned short Alds[2][128 * 64];
  __shared__ unsigned short Blds[2][128 * 64];
  const int t = threadIdx.x;
  const int l = t & 63, w = t >> 6;
  const int l15 = l & 15, l4 = l >> 4;
  const int wm = w >> 2, wn = w & 3;

  const int hwid = blockIdx.x;
  const int x = hwid & 7, loc = hwid >> 3;
  const int bm = ((x >> 1) * 8 + (loc & 7)) * 128;
  const int bn = ((x & 1) * (EPI ? 12 : 4) + (loc >> 3)) * 128;

  const int srow = t >> 3;
  const int sc = t & 7;
  using AELT = typename std::conditional<EPI == 1, float, unsigned short>::type;
  using AREG = typename std::conditional<EPI == 1, f32x8, bf16x8>::type;
  const AELT* aglp = ((const AELT*)Ain) + (size_t)(bm + srow) * 1024 + sc * 8;
  const unsigned short* bgl = Bt + (size_t)(bn + srow) * 1024 + sc * 8;
  const int wls = srow * 64 + ((sc ^ (srow & 7)) * 8);

  f32x4 acc[4][2];
#pragma unroll
  for (int i = 0; i < 4; ++i)
#pragma unroll
    for (int j = 0; j < 2; ++j) acc[i][j] = (f32x4){0.f, 0.f, 0.f, 0.f};

  AREG ra_a[2], rb_a[2];
  bf16x8 ra_b[2], rb_b[2];

#define GLOAD(RA, RB, KT)                                                     \
  _Pragma("unroll") for (int q = 0; q < 2; ++q) {                             \
    RA[q] = *(const AREG*)(aglp + (size_t)q * 65536 + (KT) * 64);             \
    RB[q] = *(const bf16x8*)(bgl + (size_t)q * 65536 + (KT) * 64);            \
  }
#define SWRITE(RA, RB, CUR)                                                   \
  _Pragma("unroll") for (int q = 0; q < 2; ++q) {                             \
    bf16x8 aw;                                                                \
    if constexpr (EPI == 1) {                                                 \
      union { unsigned int u[4]; bf16x8 v; } pk;                              \
      pk.u[0] = cvt_pk_bf16(RA[q][0], RA[q][1]);                              \
      pk.u[1] = cvt_pk_bf16(RA[q][2], RA[q][3]);                              \
      pk.u[2] = cvt_pk_bf16(RA[q][4], RA[q][5]);                              \
      pk.u[3] = cvt_pk_bf16(RA[q][6], RA[q][7]);                              \
      aw = pk.v;                                                              \
    } else {                                                                  \
      aw = RA[q];                                                             \
    }                                                                         \
    *(bf16x8*)&Alds[CUR][q * 4096 + wls] = aw;                                \
    *(bf16x8*)&Blds[CUR][q * 4096 + wls] = RB[q];                             \
  }

  GLOAD(ra_a, ra_b, 0);
  GLOAD(rb_a, rb_b, 1);
  SWRITE(ra_a, ra_b, 0);
  asm volatile("s_waitcnt lgkmcnt(0)" ::: "memory");
  __builtin_amdgcn_s_barrier();

#define GEMM_PHASE(KT, RFA, RFB, RPA, RPB)                                    \
  {                                                                           \
    const int cur_ = (KT) & 1;                                                \
    if ((KT) + 2 < 16) { GLOAD(RFA, RFB, (KT) + 2); }                         \
    __builtin_amdgcn_s_setprio(1);                                            \
    _Pragma("unroll") for (int kc = 0; kc < 2; ++kc) {                        \
      bf16x8 af[4], bv[2];                                                    \
      _Pragma("unroll") for (int i = 0; i < 4; ++i) {                         \
        int ra_ = wm * 64 + i * 16 + l15;                                     \
        af[i] = *(const bf16x8*)&Alds[cur_][ra_ * 64 +                        \
                                            (((kc * 4 + l4) ^ (l15 & 7))) * 8]; \
      }                                                                       \
      _Pragma("unroll") for (int j = 0; j < 2; ++j) {                         \
        int rb_ = wn * 32 + j * 16 + l15;                                     \
        bv[j] = *(const bf16x8*)&Blds[cur_][rb_ * 64 +                        \
                                            (((kc * 4 + l4) ^ (l15 & 7))) * 8]; \
      }                                                                       \
      _Pragma("unroll") for (int i = 0; i < 4; ++i)                           \
        _Pragma("unroll") for (int jn = 0; jn < 2; ++jn)                      \
          acc[i][jn] =                                                        \
              __builtin_amdgcn_mfma_f32_16x16x32_bf16(af[i], bv[jn],          \
                                                      acc[i][jn], 0, 0, 0);   \
    }                                                                         \
    __builtin_amdgcn_s_setprio(0);                                            \
    if ((KT) + 1 < 16) { SWRITE(RPA, RPB, cur_ ^ 1); }                        \
    asm volatile("s_waitcnt lgkmcnt(0)" ::: "memory");                        \
    __builtin_amdgcn_s_barrier();                                             \
  }

  for (int kt = 0; kt < 16; kt += 2) {
    GEMM_PHASE(kt, ra_a, ra_b, rb_a, rb_b);
    GEMM_PHASE(kt + 1, rb_a, rb_b, ra_a, ra_b);
  }
#undef GEMM_PHASE
#undef SWRITE
#undef GLOAD

#pragma unroll
  for (int i = 0; i < 4; ++i) {
#pragma unroll
    for (int jn = 0; jn < 2; ++jn) {
      int n = bn + wn * 32 + jn * 16 + l15;
      float bval = bias[n];
#pragma unroll
      for (int j = 0; j < 4; ++j) {
        int m = bm + wm * 64 + i * 16 + l4 * 4 + j;
        float v = acc[i][jn][j] + bval;
        if (EPI == 0) {
          Cf[(size_t)m * 1024 + n] = v;
        } else {
          int which = n >> 10, hh = (n >> 6) & 15, d = n & 63;
          int bb = m >> 11, pos = m & 2047;
          int bhh = bb * 16 + hh;
          if (which == 0)
            qb[((size_t)bhh * 2048 + pos) * 64 + d] = f2bf(v * 0.18033688f);  // 0.125*log2(e)
          else if (which == 1)
            kb[((size_t)bhh * 2048 + pos) * 64 + d] = f2bf(v);
          else
            vtb[((size_t)bhh * 64 + d) * 2048 + pos] = f2bf(v);
        }
      }
    }
  }
}

// ---------------- flash attention, 32x32 MFMA, swapped QK^T, P fully in-register ----
// grid 512 (XCD-swizzled -> qt,bh); 256 thr = 4 waves; wave owns 32 q rows; KVBLK=64.
// Reg-staged K/V (issue-early / ds_write-late), static dbuf, one barrier/tile.
// V stored k-PERMUTED in LDS: within each 16-k block, LDS pos p=hi*8+e holds global
// k=(e&3)+8*(e>>2)+4*hi — so the PV B-operand is ONE ds_read_b128 per (kt2,mm,dt)
// at chunk (4kt2+2mm+hi)^rsw (same conflict-free pattern as K reads; was 2x b64 with
// 4-deep bank conflicts = the measured 6.3M SQ_LDS_BANK_CONFLICT).
__global__ __launch_bounds__(256) void k_attn(const unsigned short* __restrict__ qbuf,
                                              const unsigned short* __restrict__ kbuf,
                                              const unsigned short* __restrict__ vtbuf,
                                              const float* __restrict__ biash,
                                              unsigned short* __restrict__ aout) {
  __shared__ __align__(16) unsigned short Klds[2][64 * 64];
  __shared__ __align__(16) unsigned short Vlds[2][64 * 64];

  const int t = threadIdx.x;
  const int w = t >> 6, l = t & 63;
  const int l31 = l & 31, hi = l >> 5;

  // XCD swizzle: 4 bh per XCD (K/V ~2MB -> L2-resident per XCD)
  const int bid = blockIdx.x;
  const int swzb = (bid & 7) * 64 + (bid >> 3);
  const int qt = swzb & 15;
  const int bh = swzb >> 4;
  const int h = bh & 15, b = bh >> 4;
  const int qbase = qt * 128;
  const int wq = qbase + w * 32;

  // Q B-operand regs: lane l31 = q-col, slot (hi,e) = d = 16*ds + 8*hi + e
  bf16x8 qB[4];
  {
    const unsigned short* qrow = qbuf + ((size_t)bh * 2048 + wq + l31) * 64;
#pragma unroll
    for (int ds = 0; ds < 4; ++ds) qB[ds] = *(const bf16x8*)&qrow[ds * 16 + hi * 8];
  }

  f32x16 O[2];
#pragma unroll
  for (int i = 0; i < 16; ++i) { O[0][i] = 0.f; O[1][i] = 0.f; }
  float m_run = -3e38f, l_run = 0.f;

  // staging: linear global source for K; k-permuted source for V; swizzled LDS dest
  const int c0r = t >> 3, c0c = t & 7;
  const unsigned short* kg = kbuf + ((size_t)bh * 2048 + c0r) * 64 + c0c * 8;
  // V permuted source: this thread's LDS chunk c0c (positions c0c*8..+7) needs global
  // k = (c0c>>1)*16 + (c0c&1)*4 + {0,1,2,3, 8,9,10,11}
  const unsigned short* vgp =
      vtbuf + ((size_t)bh * 64 + c0r) * 2048 + (c0c >> 1) * 16 + (c0c & 1) * 4;
  const int wKV = c0r * 64 + ((c0c ^ (c0r & 7)) * 8);

#define VLOADP(DST, OFF)                                                      \
  {                                                                           \
    bf16x4 lo_ = *(const bf16x4*)(vgp + (OFF));                               \
    bf16x4 hi_ = *(const bf16x4*)(vgp + (OFF) + 8);                           \
    DST = __builtin_shufflevector(lo_, hi_, 0, 1, 2, 3, 4, 5, 6, 7);          \
  }

  // prologue: stage tile 0
  {
    bf16x8 k0 = *(const bf16x8*)(kg);
    bf16x8 k1 = *(const bf16x8*)(kg + 32 * 64);
    bf16x8 v0, v1;
    VLOADP(v0, 0);
    VLOADP(v1, 32 * 2048);
    *(bf16x8*)&Klds[0][wKV] = k0;
    *(bf16x8*)&Klds[0][wKV + 2048] = k1;
    *(bf16x8*)&Vlds[0][wKV] = v0;
    *(bf16x8*)&Vlds[0][wKV + 2048] = v1;
  }
  __syncthreads();

  // per-lane global bias base: value(kt2,g,r) = bgl[kt*64 + 32*kt2 + 8*g + r]
  const float* bgl = biash + h * 4096 + 2047 - (wq + l31) + 4 * hi;

  for (int kt = 0; kt < 32; ++kt) {
    const int cur = kt & 1;

    // issue-early: next tile global loads into regs
    bf16x8 kst0, kst1, vst0, vst1;
    if (kt < 31) {
      const unsigned short* kga = kg + (size_t)(kt + 1) * 4096;
      const int voff = (kt + 1) * 64;
      kst0 = *(const bf16x8*)(kga);
      kst1 = *(const bf16x8*)(kga + 32 * 64);
      VLOADP(vst0, voff);
      VLOADP(vst1, voff + 32 * 2048);
    }
    const int kbase = kt * 64;

    // bias loads (L1-resident; 4B-aligned 16B loads) — independent, issue early
    f32x4 bq[2][4];
#pragma unroll
    for (int kt2 = 0; kt2 < 2; ++kt2)
#pragma unroll
      for (int g = 0; g < 4; ++g)
        __builtin_memcpy(&bq[kt2][g], &bgl[kbase + 32 * kt2 + 8 * g], 16);

    // QK^T swapped: sacc C-layout: col=l31=q, row(reg)=(reg&3)+8*(reg>>2)+4*hi = k-local
    f32x16 sacc[2];
#pragma unroll
    for (int i = 0; i < 16; ++i) { sacc[0][i] = 0.f; sacc[1][i] = 0.f; }
    __builtin_amdgcn_s_setprio(1);
#pragma unroll
    for (int kt2 = 0; kt2 < 2; ++kt2) {
      int row = kt2 * 32 + l31;
      int rsw = row & 7;
#pragma unroll
      for (int ds = 0; ds < 4; ++ds) {
        bf16x8 ka = *(const bf16x8*)&Klds[cur][row * 64 + (((2 * ds + hi) ^ rsw) * 8)];
        sacc[kt2] = __builtin_amdgcn_mfma_f32_32x32x16_bf16(ka, qB[ds], sacc[kt2], 0, 0, 0);
      }
    }
    __builtin_amdgcn_s_setprio(0);

    // bias add
#pragma unroll
    for (int kt2 = 0; kt2 < 2; ++kt2)
#pragma unroll
      for (int g = 0; g < 4; ++g)
#pragma unroll
        for (int r = 0; r < 4; ++r) sacc[kt2][4 * g + r] += bq[kt2][g][r];

    // max over own 32 + 1 cross-half swap
    float mx;
    {
      float q0 = fmaxf(fmaxf(sacc[0][0], sacc[0][1]), fmaxf(sacc[0][2], sacc[0][3]));
      float q1 = fmaxf(fmaxf(sacc[0][4], sacc[0][5]), fmaxf(sacc[0][6], sacc[0][7]));
      float q2 = fmaxf(fmaxf(sacc[0][8], sacc[0][9]), fmaxf(sacc[0][10], sacc[0][11]));
      float q3 = fmaxf(fmaxf(sacc[0][12], sacc[0][13]), fmaxf(sacc[0][14], sacc[0][15]));
      float q4 = fmaxf(fmaxf(sacc[1][0], sacc[1][1]), fmaxf(sacc[1][2], sacc[1][3]));
      float q5 = fmaxf(fmaxf(sacc[1][4], sacc[1][5]), fmaxf(sacc[1][6], sacc[1][7]));
      float q6 = fmaxf(fmaxf(sacc[1][8], sacc[1][9]), fmaxf(sacc[1][10], sacc[1][11]));
      float q7 = fmaxf(fmaxf(sacc[1][12], sacc[1][13]), fmaxf(sacc[1][14], sacc[1][15]));
      mx = fmaxf(fmaxf(fmaxf(q0, q1), fmaxf(q2, q3)), fmaxf(fmaxf(q4, q5), fmaxf(q6, q7)));
      mx = fmaxf(mx, __shfl_xor(mx, 32));
    }

    // defer-max rescale (THR=8, log2 domain)
    if (__any(mx > m_run + 8.f)) {
      float mnew = fmaxf(m_run, mx);
      float alpha = exp2_fast(m_run - mnew);
      m_run = mnew;
      l_run *= alpha;
#pragma unroll
      for (int g = 0; g < 4; ++g)
#pragma unroll
        for (int r = 0; r < 4; ++r) {
          float a_lo = __shfl(alpha, 8 * g + r);
          float a_hi = __shfl(alpha, 8 * g + r + 4);
          float aq = hi ? a_hi : a_lo;
          O[0][4 * g + r] *= aq;
          O[1][4 * g + r] *= aq;
        }
    }

    // exp + row-sum (own 32 + 1 swap)
#pragma unroll
    for (int kt2 = 0; kt2 < 2; ++kt2)
#pragma unroll
      for (int i = 0; i < 16; ++i) sacc[kt2][i] = exp2_fast(sacc[kt2][i] - m_run);
    {
      float s0 = (sacc[0][0] + sacc[0][1]) + (sacc[0][2] + sacc[0][3]);
      float s1 = (sacc[0][4] + sacc[0][5]) + (sacc[0][6] + sacc[0][7]);
      float s2 = (sacc[0][8] + sacc[0][9]) + (sacc[0][10] + sacc[0][11]);
      float s3 = (sacc[0][12] + sacc[0][13]) + (sacc[0][14] + sacc[0][15]);
      float s4 = (sacc[1][0] + sacc[1][1]) + (sacc[1][2] + sacc[1][3]);
      float s5 = (sacc[1][4] + sacc[1][5]) + (sacc[1][6] + sacc[1][7]);
      float s6 = (sacc[1][8] + sacc[1][9]) + (sacc[1][10] + sacc[1][11]);
      float s7 = (sacc[1][12] + sacc[1][13]) + (sacc[1][14] + sacc[1][15]);
      float rs = ((s0 + s1) + (s2 + s3)) + ((s4 + s5) + (s6 + s7));
      rs += __shfl_xor(rs, 32);
      l_run += rs;
    }

    // P pack: PV A-operand = own regs pairwise cvt_pk (sigma-permuted contract slots)
    bf16x8 pa[2][2];
#pragma unroll
    for (int kt2 = 0; kt2 < 2; ++kt2)
#pragma unroll
      for (int mm = 0; mm < 2; ++mm) {
        union { unsigned int u[4]; bf16x8 v; } pk;
        pk.u[0] = cvt_pk_bf16(sacc[kt2][8 * mm + 0], sacc[kt2][8 * mm + 1]);
        pk.u[1] = cvt_pk_bf16(sacc[kt2][8 * mm + 2], sacc[kt2][8 * mm + 3]);
        pk.u[2] = cvt_pk_bf16(sacc[kt2][8 * mm + 4], sacc[kt2][8 * mm + 5]);
        pk.u[3] = cvt_pk_bf16(sacc[kt2][8 * mm + 6], sacc[kt2][8 * mm + 7]);
        pa[kt2][mm] = pk.v;
      }

    // PV: O[dt] += P * V ; V slot (hi,e): k = 32*kt2 + 16*mm + 8*(e>>2) + 4*hi + (e&3)
    // = single b128 at permuted chunk (4*kt2 + 2*mm + hi) ^ rsw
    __builtin_amdgcn_s_setprio(1);
#pragma unroll
    for (int dt = 0; dt < 2; ++dt) {
      int row = dt * 32 + l31;
      int rsw = row & 7;
#pragma unroll
      for (int kt2 = 0; kt2 < 2; ++kt2)
#pragma unroll
        for (int mm = 0; mm < 2; ++mm) {
          bf16x8 vb =
              *(const bf16x8*)&Vlds[cur][row * 64 + (((4 * kt2 + 2 * mm + hi) ^ rsw) * 8)];
          O[dt] = __builtin_amdgcn_mfma_f32_32x32x16_bf16(pa[kt2][mm], vb, O[dt], 0, 0, 0);
        }
    }
    __builtin_amdgcn_s_setprio(0);

    // write-late: publish next tile
    if (kt < 31) {
      *(bf16x8*)&Klds[cur ^ 1][wKV] = kst0;
      *(bf16x8*)&Klds[cur ^ 1][wKV + 2048] = kst1;
      *(bf16x8*)&Vlds[cur ^ 1][wKV] = vst0;
      *(bf16x8*)&Vlds[cur ^ 1][wKV + 2048] = vst1;
    }
    __syncthreads();
  }
#undef VLOADP

  // epilogue: gather 1/l per O-row, scale, store (O lane = d-col)
  {
    float linv = 1.f / l_run;
#pragma unroll
    for (int g = 0; g < 4; ++g)
#pragma unroll
      for (int r = 0; r < 4; ++r) {
        float v_lo = __shfl(linv, 8 * g + r);
        float v_hi = __shfl(linv, 8 * g + r + 4);
        float sc = hi ? v_hi : v_lo;
        int q = wq + 8 * g + r + 4 * hi;
        size_t base = ((size_t)b * 2048 + q) * 1024 + h * 64 + l31;
        aout[base] = f2bf(O[0][4 * g + r] * sc);
        aout[base + 32] = f2bf(O[1][4 * g + r] * sc);
      }
  }
}

// ---------------- launch ----------------

extern "C" void kernel_launch(void* const* d_in, const int* in_sizes, int n_in,
                              void* d_out, int out_size, void* d_ws, size_t ws_size,
                              hipStream_t stream) {
  const float* x = (const float*)d_in[0];
  const float* qkv_w = (const float*)d_in[1];
  const float* qkv_b = (const float*)d_in[2];
  const float* proj_w = (const float*)d_in[3];
  const float* proj_b = (const float*)d_in[4];
  const float* bias_table = (const float*)d_in[5];
  float* out = (float*)d_out;

  char* ws = (char*)d_ws;
  unsigned short* attn_out = (unsigned short*)(ws);                    // 8 MB
  unsigned short* wqkv = (unsigned short*)(ws + (size_t)(8u << 20));   // 6 MB
  unsigned short* wproj = (unsigned short*)(ws + (size_t)(14u << 20)); // 2 MB
  unsigned short* qb = (unsigned short*)(ws + (size_t)(16u << 20));    // 8 MB
  unsigned short* kb = (unsigned short*)(ws + (size_t)(24u << 20));    // 8 MB
  unsigned short* vtb = (unsigned short*)(ws + (size_t)(32u << 20));   // 8 MB
  float* biash = (float*)(ws + (size_t)(40u << 20));                   // 256 KB

  k_transpose_bf16<<<dim3(96, 32), dim3(32, 8), 0, stream>>>(qkv_w, wqkv, 1024, 3072);
  k_transpose_bf16<<<dim3(32, 32), dim3(32, 8), 0, stream>>>(proj_w, wproj, 1024, 1024);
  k_bias_cols<<<dim3(256), dim3(256), 0, stream>>>(bias_table, biash);

  k_gemm<1><<<dim3(768), dim3(512), 0, stream>>>((const void*)x, wqkv, qkv_b, nullptr, qb, kb,
                                                 vtb);
  k_attn<<<dim3(512), dim3(256), 0, stream>>>(qb, kb, vtb, biash, attn_out);
  k_gemm<0><<<dim3(256), dim3(512), 0, stream>>>((const void*)attn_out, wproj, proj_b, out,
                                                 nullptr, nullptr, nullptr);
}